// Round 3
// baseline (426.810 us; speedup 1.0000x reference)
//
#include <hip/hip_runtime.h>
#include <hip/hip_bf16.h>
#include <stdint.h>

#define Dd 1024
#define Hd 2048
#define Od 1024
#define Ed 8
#define Nd 4096

typedef __bf16 bf16x8 __attribute__((ext_vector_type(8)));
typedef float f32x4 __attribute__((ext_vector_type(4)));

__device__ __forceinline__ void gload16(const void* g, void* l) {
  __builtin_amdgcn_global_load_lds(
      (const __attribute__((address_space(1))) void*)g,
      (__attribute__((address_space(3))) void*)l, 16, 0, 0);
}

__device__ __forceinline__ unsigned short f2bf(float f) {
  __hip_bfloat16 h = __float2bfloat16(f);
  return *reinterpret_cast<unsigned short*>(&h);
}

// ---------- f32 -> bf16 conversion, 8 elems / thread ----------
__global__ void cvt_kernel(const float* __restrict__ in,
                           unsigned short* __restrict__ out, int ngroups) {
  int stride = gridDim.x * blockDim.x;
  for (int g = blockIdx.x * blockDim.x + threadIdx.x; g < ngroups; g += stride) {
    const float4* p = (const float4*)(in + (size_t)g * 8);
    float4 a = p[0], b = p[1];
    unsigned short o[8];
    o[0] = f2bf(a.x); o[1] = f2bf(a.y); o[2] = f2bf(a.z); o[3] = f2bf(a.w);
    o[4] = f2bf(b.x); o[5] = f2bf(b.y); o[6] = f2bf(b.z); o[7] = f2bf(b.w);
    *(int4*)(out + (size_t)g * 8) = *(int4*)o;
  }
}

// ---------- router (also emits xb bf16) ----------
__global__ void router_kernel(const float* __restrict__ x, const float* __restrict__ Wr,
                              const float* __restrict__ br, float* __restrict__ route,
                              unsigned short* __restrict__ xb) {
  const int n = blockIdx.x;
  const int t = threadIdx.x;  // 256
  __shared__ float xs[Dd];
  float4 v = *(const float4*)&x[(size_t)n * Dd + t * 4];
  *(float4*)&xs[t * 4] = v;
  unsigned short o[4] = {f2bf(v.x), f2bf(v.y), f2bf(v.z), f2bf(v.w)};
  *(uint2*)&xb[(size_t)n * Dd + t * 4] = *(const uint2*)o;
  __syncthreads();
  float p[Ed];
  #pragma unroll
  for (int e = 0; e < Ed; ++e) p[e] = 0.f;
  for (int d = t; d < Dd; d += 256) {
    float xv = xs[d];
    #pragma unroll
    for (int e = 0; e < Ed; ++e) p[e] += xv * Wr[e * Dd + d];
  }
  __shared__ float red[Ed][4];
  const int lane = t & 63, wid = t >> 6;
  #pragma unroll
  for (int e = 0; e < Ed; ++e) {
    float vv = p[e];
    for (int off = 32; off > 0; off >>= 1) vv += __shfl_down(vv, off);
    if (lane == 0) red[e][wid] = vv;
  }
  __syncthreads();
  if (t == 0) {
    float lg[Ed], mx = -1e30f;
    #pragma unroll
    for (int e = 0; e < Ed; ++e) {
      lg[e] = red[e][0] + red[e][1] + red[e][2] + red[e][3] + br[e];
      mx = fmaxf(mx, lg[e]);
    }
    float s = 0.f;
    #pragma unroll
    for (int e = 0; e < Ed; ++e) { lg[e] = expf(lg[e] - mx); s += lg[e]; }
    float inv = 1.f / s;
    #pragma unroll
    for (int e = 0; e < Ed; ++e) route[(size_t)n * Ed + e] = lg[e] * inv;
  }
}

// ---------- out init: out[n,o] = sum_e route[n,e] * b2[e,o] ----------
__global__ void init_out_kernel(const float* __restrict__ route, const float* __restrict__ b2,
                                float* __restrict__ out) {
  const int idx = blockIdx.x * 256 + threadIdx.x;
  const int n = idx >> 10, o = idx & (Od - 1);
  float s = 0.f;
  #pragma unroll
  for (int e = 0; e < Ed; ++e) s += route[(size_t)n * Ed + e] * b2[e * Od + o];
  out[idx] = s;
}

#define LGKM0 do { asm volatile("s_waitcnt lgkmcnt(0)" ::: "memory"); \
                   __builtin_amdgcn_sched_barrier(0); } while (0)

// ============ 256x256 8-phase GEMM (MODE 0 = gemm1, 1 = gemm2) ============
// A row-major [M][K], B row-major [N][K] (B^T form), both bf16.
// LDS: As/Bs [2 buf][256 rows][64 cols], row-permuted + 16B-chunk XOR swizzle.
// Deep prefetch: during tile U, stage ALL of tile U+2 into cur buf, each unit
// placed in the phase right after its last LDS-read:
//   A0,B0 last read q0 -> staged q1 ; A1 last read q1 -> staged q2 ;
//   B1 last read q2 -> staged q3.  Boundary: vmcnt(8) (leaves U+2's 8 loads
//   in flight, drains U+1 which was staged during tile U-1).
template <int MODE>
__global__ __launch_bounds__(512, 2) void gemm8p(
    const unsigned short* __restrict__ Ag,
    const unsigned short* __restrict__ Bg,
    const float* __restrict__ bias,
    const float* __restrict__ route,
    void* __restrict__ Cout,
    int n0, int ncRows, int ngx) {
  extern __shared__ unsigned short smem[];
  unsigned short* As = smem;            // 2 x 16384
  unsigned short* Bs = smem + 32768;    // 2 x 16384

  // bijective XCD swizzle (nwg % 8 == 0 by construction)
  const int nwg = gridDim.x;
  const int orig = blockIdx.x;
  const int q8 = nwg >> 3;
  const int wg = (orig & 7) * q8 + (orig >> 3);
  const int bx = wg % ngx;
  const int rem = wg / ngx;
  int by, ez;
  if (MODE == 0) { by = rem & 7; ez = rem >> 3; }       // by in [0,8), expert in [0,8)
  else           { by = rem & 3; ez = rem >> 2; }       // by in [0,4), expert in [0,8)

  const int tid = threadIdx.x;
  const int wid = tid >> 6, lane = tid & 63;
  const int wm = wid >> 2, wn = wid & 3;

  const int trow = tid >> 3;                       // row-within-strip for staging
  const int tcs = ((tid & 7) ^ (trow & 7)) * 8;    // inverse-swizzled source col (elems)

  const int NT = (MODE == 0) ? (Dd / 64) : (Hd / 64);

  auto stageA = [&](int buf, int kt, int mh) {
    #pragma unroll
    for (int s = 0; s < 2; ++s) {
      const int pa = mh * 128 + s * 64 + trow;
      const int m = ((pa >> 6) & 1) * 128 + ((pa >> 7) & 1) * 64 + (pa & 63);
      const unsigned short* g;
      if (MODE == 0) {
        g = Ag + (size_t)(n0 + bx * 256 + m) * Dd + kt * 64 + tcs;
      } else {
        g = Ag + (size_t)ez * ncRows * Hd + (size_t)(bx * 256 + m) * Hd + kt * 64 + tcs;
      }
      gload16(g, &As[(size_t)buf * 16384 + (size_t)(mh * 128 + s * 64) * 64 + wid * 512]);
    }
  };
  auto stageB = [&](int buf, int kt, int nh) {
    #pragma unroll
    for (int s = 0; s < 2; ++s) {
      const int pb = nh * 128 + s * 64 + trow;
      const int n = ((pb >> 5) & 3) * 64 + ((pb >> 7) & 1) * 32 + (pb & 31);
      const unsigned short* g;
      if (MODE == 0) {
        g = Bg + (size_t)ez * Hd * Dd + (size_t)(by * 256 + n) * Dd + kt * 64 + tcs;
      } else {
        g = Bg + (size_t)ez * Od * Hd + (size_t)(by * 256 + n) * Hd + kt * 64 + tcs;
      }
      gload16(g, &Bs[(size_t)buf * 16384 + (size_t)(nh * 128 + s * 64) * 64 + wid * 512]);
    }
  };

  const int laneRow = lane & 15;
  const int swzc[2] = { ((lane >> 4) ^ (lane & 7)) << 3,
                        (((lane >> 4) + 4) ^ (lane & 7)) << 3 };
  const int aRowBase = (wm * 64 + laneRow) * 64;
  const int bRowBase = (wn * 32 + laneRow) * 64;

  auto rdA = [&](int buf, int mh, int mi, int kk) -> bf16x8 {
    const int addr = buf * 16384 + aRowBase + (mh * 128 + mi * 16) * 64 + swzc[kk];
    return *(const bf16x8*)&As[addr];
  };
  auto rdB = [&](int buf, int nh, int ni, int kk) -> bf16x8 {
    const int addr = buf * 16384 + bRowBase + (nh * 128 + ni * 16) * 64 + swzc[kk];
    return *(const bf16x8*)&Bs[addr];
  };

  f32x4 acc[8][4];
  #pragma unroll
  for (int i = 0; i < 8; ++i)
    #pragma unroll
    for (int j = 0; j < 4; ++j) acc[i][j] = (f32x4){0.f, 0.f, 0.f, 0.f};
  bf16x8 a0[4][2], a1[4][2], b0[2][2], b1[2][2];

  // prologue: tile0 -> buf0, tile1 -> buf1 (8 loads each); wait tile0 only
  stageA(0, 0, 0); stageB(0, 0, 0); stageA(0, 0, 1); stageB(0, 0, 1);
  stageA(1, 1, 0); stageB(1, 1, 0); stageA(1, 1, 1); stageB(1, 1, 1);
  asm volatile("s_waitcnt vmcnt(8)" ::: "memory");
  __builtin_amdgcn_sched_barrier(0);
  __builtin_amdgcn_s_barrier();

  for (int U = 0; U < NT; ++U) {
    const int buf = U & 1;
    const bool pf = (U + 2 < NT);
    // ---- q0: reads A0,B0 ; no stage
    #pragma unroll
    for (int mi = 0; mi < 4; ++mi) { a0[mi][0] = rdA(buf, 0, mi, 0); a0[mi][1] = rdA(buf, 0, mi, 1); }
    #pragma unroll
    for (int ni = 0; ni < 2; ++ni) { b0[ni][0] = rdB(buf, 0, ni, 0); b0[ni][1] = rdB(buf, 0, ni, 1); }
    __builtin_amdgcn_s_barrier();
    LGKM0;
    __builtin_amdgcn_s_setprio(1);
    #pragma unroll
    for (int mi = 0; mi < 4; ++mi)
      #pragma unroll
      for (int ni = 0; ni < 2; ++ni) {
        acc[mi][ni] = __builtin_amdgcn_mfma_f32_16x16x32_bf16(a0[mi][0], b0[ni][0], acc[mi][ni], 0, 0, 0);
        acc[mi][ni] = __builtin_amdgcn_mfma_f32_16x16x32_bf16(a0[mi][1], b0[ni][1], acc[mi][ni], 0, 0, 0);
      }
    __builtin_amdgcn_s_setprio(0);
    __builtin_amdgcn_s_barrier();
    // ---- q1: reads A1 ; stage U+2: A0,B0 (regions last read at q0)
    #pragma unroll
    for (int mi = 0; mi < 4; ++mi) { a1[mi][0] = rdA(buf, 1, mi, 0); a1[mi][1] = rdA(buf, 1, mi, 1); }
    if (pf) { stageA(buf, U + 2, 0); stageB(buf, U + 2, 0); }
    __builtin_amdgcn_s_barrier();
    LGKM0;
    __builtin_amdgcn_s_setprio(1);
    #pragma unroll
    for (int mi = 0; mi < 4; ++mi)
      #pragma unroll
      for (int ni = 0; ni < 2; ++ni) {
        acc[4 + mi][ni] = __builtin_amdgcn_mfma_f32_16x16x32_bf16(a1[mi][0], b0[ni][0], acc[4 + mi][ni], 0, 0, 0);
        acc[4 + mi][ni] = __builtin_amdgcn_mfma_f32_16x16x32_bf16(a1[mi][1], b0[ni][1], acc[4 + mi][ni], 0, 0, 0);
      }
    __builtin_amdgcn_s_setprio(0);
    __builtin_amdgcn_s_barrier();
    // ---- q2: reads B1 ; stage U+2: A1 (last read at q1)
    #pragma unroll
    for (int ni = 0; ni < 2; ++ni) { b1[ni][0] = rdB(buf, 1, ni, 0); b1[ni][1] = rdB(buf, 1, ni, 1); }
    if (pf) stageA(buf, U + 2, 1);
    __builtin_amdgcn_s_barrier();
    LGKM0;
    __builtin_amdgcn_s_setprio(1);
    #pragma unroll
    for (int mi = 0; mi < 4; ++mi)
      #pragma unroll
      for (int ni = 0; ni < 2; ++ni) {
        acc[4 + mi][2 + ni] = __builtin_amdgcn_mfma_f32_16x16x32_bf16(a1[mi][0], b1[ni][0], acc[4 + mi][2 + ni], 0, 0, 0);
        acc[4 + mi][2 + ni] = __builtin_amdgcn_mfma_f32_16x16x32_bf16(a1[mi][1], b1[ni][1], acc[4 + mi][2 + ni], 0, 0, 0);
      }
    __builtin_amdgcn_s_setprio(0);
    __builtin_amdgcn_s_barrier();
    // ---- q3: no reads ; stage U+2: B1 (last read at q2)
    if (pf) stageB(buf, U + 2, 1);
    __builtin_amdgcn_s_barrier();
    __builtin_amdgcn_s_setprio(1);
    #pragma unroll
    for (int mi = 0; mi < 4; ++mi)
      #pragma unroll
      for (int ni = 0; ni < 2; ++ni) {
        acc[mi][2 + ni] = __builtin_amdgcn_mfma_f32_16x16x32_bf16(a0[mi][0], b1[ni][0], acc[mi][2 + ni], 0, 0, 0);
        acc[mi][2 + ni] = __builtin_amdgcn_mfma_f32_16x16x32_bf16(a0[mi][1], b1[ni][1], acc[mi][2 + ni], 0, 0, 0);
      }
    __builtin_amdgcn_s_setprio(0);
    // boundary: drain tile U+1 (staged during U-1); U+2's 8 loads stay in flight
    if (pf) {
      asm volatile("s_waitcnt vmcnt(8)" ::: "memory");
    } else if (U + 1 < NT) {
      asm volatile("s_waitcnt vmcnt(0)" ::: "memory");
    }
    __builtin_amdgcn_sched_barrier(0);
    __builtin_amdgcn_s_barrier();
  }

  // ---------------- epilogue ----------------
  if (MODE == 0) {
    unsigned short* hs = (unsigned short*)Cout;
    unsigned short* base = hs + (size_t)ez * ((size_t)ncRows * Hd);
    #pragma unroll
    for (int M = 0; M < 8; ++M) {
      const int mh = M >> 2, mi = M & 3;
      const int row = bx * 256 + wm * 128 + mh * 64 + mi * 16 + (lane >> 4) * 4;
      float rw[4];
      #pragma unroll
      for (int j = 0; j < 4; ++j) rw[j] = route[(size_t)(n0 + row + j) * Ed + ez];
      #pragma unroll
      for (int N = 0; N < 4; ++N) {
        const int nh = N >> 1, ni = N & 1;
        const int col = by * 256 + wn * 64 + nh * 32 + ni * 16 + (lane & 15);
        const float bv = bias[ez * Hd + col];
        #pragma unroll
        for (int j = 0; j < 4; ++j) {
          float v = acc[M][N][j] + bv;
          v = fmaxf(v, 0.f);
          v = v * v * rw[j];
          base[(size_t)(row + j) * Hd + col] = f2bf(v);
        }
      }
    }
  } else {
    float* out = (float*)Cout;
    #pragma unroll
    for (int M = 0; M < 8; ++M) {
      const int mh = M >> 2, mi = M & 3;
      const int row = n0 + bx * 256 + wm * 128 + mh * 64 + mi * 16 + (lane >> 4) * 4;
      #pragma unroll
      for (int N = 0; N < 4; ++N) {
        const int nh = N >> 1, ni = N & 1;
        const int col = by * 256 + wn * 64 + nh * 32 + ni * 16 + (lane & 15);
        #pragma unroll
        for (int j = 0; j < 4; ++j)
          atomicAdd(out + (size_t)(row + j) * Od + col, acc[M][N][j]);
      }
    }
  }
}

extern "C" void kernel_launch(void* const* d_in, const int* in_sizes, int n_in,
                              void* d_out, int out_size, void* d_ws, size_t ws_size,
                              hipStream_t stream) {
  const float* x  = (const float*)d_in[0];
  const float* Wr = (const float*)d_in[1];
  const float* br = (const float*)d_in[2];
  const float* W1 = (const float*)d_in[3];
  const float* b1 = (const float*)d_in[4];
  const float* W2 = (const float*)d_in[5];
  const float* b2 = (const float*)d_in[6];
  float* out = (float*)d_out;

  char* ws = (char*)d_ws;
  size_t off = 0;
  float* route = (float*)(ws + off);                 off += (size_t)Nd * Ed * 4;
  unsigned short* xb  = (unsigned short*)(ws + off); off += (size_t)Nd * Dd * 2;
  unsigned short* w1b = (unsigned short*)(ws + off); off += (size_t)Ed * Hd * Dd * 2;
  unsigned short* w2b = (unsigned short*)(ws + off); off += (size_t)Ed * Od * Hd * 2;
  unsigned short* hs  = (unsigned short*)(ws + off);

  size_t remain = (ws_size > off) ? (ws_size - off) : 0;
  const size_t perRow = (size_t)Ed * Hd * 2;  // bytes of hs per token row
  long long ncMax = (long long)(remain / perRow);
  int NC = (int)(ncMax & ~255LL);
  if (NC > Nd) NC = Nd;
  if (NC < 256) NC = 256;

  hipFuncSetAttribute(reinterpret_cast<const void*>(&gemm8p<0>),
                      hipFuncAttributeMaxDynamicSharedMemorySize, 131072);
  hipFuncSetAttribute(reinterpret_cast<const void*>(&gemm8p<1>),
                      hipFuncAttributeMaxDynamicSharedMemorySize, 131072);

  cvt_kernel<<<2048, 256, 0, stream>>>(W1, w1b, Ed * Hd * Dd / 8);
  cvt_kernel<<<2048, 256, 0, stream>>>(W2, w2b, Ed * Od * Hd / 8);
  router_kernel<<<Nd, 256, 0, stream>>>(x, Wr, br, route, xb);
  init_out_kernel<<<Nd * Od / 256, 256, 0, stream>>>(route, b2, out);

  for (int n0 = 0; n0 < Nd; n0 += NC) {
    int nc = (NC < (Nd - n0)) ? NC : (Nd - n0);
    int ngx = nc / 256;
    gemm8p<0><<<ngx * 8 * Ed, 512, 131072, stream>>>(xb, w1b, b1, route, hs, n0, nc, ngx);
    gemm8p<1><<<ngx * 4 * Ed, 512, 131072, stream>>>(hs, w2b, nullptr, nullptr, out, n0, nc, ngx);
  }
}

// Round 4
// 406.594 us; speedup vs baseline: 1.0497x; 1.0497x over previous
//
#include <hip/hip_runtime.h>
#include <hip/hip_bf16.h>
#include <stdint.h>

#define Dd 1024
#define Hd 2048
#define Od 1024
#define Ed 8
#define Nd 4096

typedef __bf16 bf16x8 __attribute__((ext_vector_type(8)));
typedef float f32x4 __attribute__((ext_vector_type(4)));

__device__ __forceinline__ void gload16(const void* g, void* l) {
  __builtin_amdgcn_global_load_lds(
      (const __attribute__((address_space(1))) void*)g,
      (__attribute__((address_space(3))) void*)l, 16, 0, 0);
}

__device__ __forceinline__ unsigned short f2bf(float f) {
  __hip_bfloat16 h = __float2bfloat16(f);
  return *reinterpret_cast<unsigned short*>(&h);
}

// ---------- f32 -> bf16 conversion, 8 elems / thread ----------
__global__ void cvt_kernel(const float* __restrict__ in,
                           unsigned short* __restrict__ out, int ngroups) {
  int stride = gridDim.x * blockDim.x;
  for (int g = blockIdx.x * blockDim.x + threadIdx.x; g < ngroups; g += stride) {
    const float4* p = (const float4*)(in + (size_t)g * 8);
    float4 a = p[0], b = p[1];
    unsigned short o[8];
    o[0] = f2bf(a.x); o[1] = f2bf(a.y); o[2] = f2bf(a.z); o[3] = f2bf(a.w);
    o[4] = f2bf(b.x); o[5] = f2bf(b.y); o[6] = f2bf(b.z); o[7] = f2bf(b.w);
    *(int4*)(out + (size_t)g * 8) = *(int4*)o;
  }
}

// ---------- router (also emits xb bf16) ----------
__global__ void router_kernel(const float* __restrict__ x, const float* __restrict__ Wr,
                              const float* __restrict__ br, float* __restrict__ route,
                              unsigned short* __restrict__ xb) {
  const int n = blockIdx.x;
  const int t = threadIdx.x;  // 256
  __shared__ float xs[Dd];
  float4 v = *(const float4*)&x[(size_t)n * Dd + t * 4];
  *(float4*)&xs[t * 4] = v;
  unsigned short o[4] = {f2bf(v.x), f2bf(v.y), f2bf(v.z), f2bf(v.w)};
  *(uint2*)&xb[(size_t)n * Dd + t * 4] = *(const uint2*)o;
  __syncthreads();
  float p[Ed];
  #pragma unroll
  for (int e = 0; e < Ed; ++e) p[e] = 0.f;
  for (int d = t; d < Dd; d += 256) {
    float xv = xs[d];
    #pragma unroll
    for (int e = 0; e < Ed; ++e) p[e] += xv * Wr[e * Dd + d];
  }
  __shared__ float red[Ed][4];
  const int lane = t & 63, wid = t >> 6;
  #pragma unroll
  for (int e = 0; e < Ed; ++e) {
    float vv = p[e];
    for (int off = 32; off > 0; off >>= 1) vv += __shfl_down(vv, off);
    if (lane == 0) red[e][wid] = vv;
  }
  __syncthreads();
  if (t == 0) {
    float lg[Ed], mx = -1e30f;
    #pragma unroll
    for (int e = 0; e < Ed; ++e) {
      lg[e] = red[e][0] + red[e][1] + red[e][2] + red[e][3] + br[e];
      mx = fmaxf(mx, lg[e]);
    }
    float s = 0.f;
    #pragma unroll
    for (int e = 0; e < Ed; ++e) { lg[e] = expf(lg[e] - mx); s += lg[e]; }
    float inv = 1.f / s;
    #pragma unroll
    for (int e = 0; e < Ed; ++e) route[(size_t)n * Ed + e] = lg[e] * inv;
  }
}

// ---------- out init: out[n,o] = sum_e route[n,e] * b2[e,o] ----------
__global__ void init_out_kernel(const float* __restrict__ route, const float* __restrict__ b2,
                                float* __restrict__ out) {
  const int idx = blockIdx.x * 256 + threadIdx.x;
  const int n = idx >> 10, o = idx & (Od - 1);
  float s = 0.f;
  #pragma unroll
  for (int e = 0; e < Ed; ++e) s += route[(size_t)n * Ed + e] * b2[e * Od + o];
  out[idx] = s;
}

#define LGKM0 do { asm volatile("s_waitcnt lgkmcnt(0)" ::: "memory"); \
                   __builtin_amdgcn_sched_barrier(0); } while (0)

// ============ 256x256 8-phase GEMM (MODE 0 = gemm1, 1 = gemm2) ============
// R2's proven mixed-depth schedule:
//   q0 stages A-mh0(U+1)->nbuf ; q1 stages B-nh1(U+1)->nbuf ;
//   q2 stages B-nh0(U+2)->buf  ; q3 stages A-mh1(U+2)->buf ;
//   boundary vmcnt(4) keeps the 4 newest (U+2's) loads in flight.
// MODE 1 is single-expert (ez in [0,8)), NT=32, atomics into out.
template <int MODE>
__global__ __launch_bounds__(512, 2) void gemm8p(
    const unsigned short* __restrict__ Ag,
    const unsigned short* __restrict__ Bg,
    const float* __restrict__ bias,
    const float* __restrict__ route,
    void* __restrict__ Cout,
    int n0, int ncRows, int ngx) {
  extern __shared__ unsigned short smem[];
  unsigned short* As = smem;            // 2 x 16384
  unsigned short* Bs = smem + 32768;    // 2 x 16384

  // bijective XCD swizzle (nwg % 8 == 0 by construction)
  const int nwg = gridDim.x;
  const int orig = blockIdx.x;
  const int q8 = nwg >> 3;
  const int wg = (orig & 7) * q8 + (orig >> 3);
  const int bx = wg % ngx;
  const int rem = wg / ngx;
  int by, ez;
  if (MODE == 0) { by = rem & 7; ez = rem >> 3; }       // by in [0,8), expert in [0,8)
  else           { by = rem & 3; ez = rem >> 2; }       // by in [0,4), expert in [0,8)

  const int tid = threadIdx.x;
  const int wid = tid >> 6, lane = tid & 63;
  const int wm = wid >> 2, wn = wid & 3;

  const int trow = tid >> 3;                       // row-within-strip for staging
  const int tcs = ((tid & 7) ^ (trow & 7)) * 8;    // inverse-swizzled source col (elems)

  const int NT = (MODE == 0) ? (Dd / 64) : (Hd / 64);

  auto stageA = [&](int buf, int kt, int mh) {
    #pragma unroll
    for (int s = 0; s < 2; ++s) {
      const int pa = mh * 128 + s * 64 + trow;
      const int m = ((pa >> 6) & 1) * 128 + ((pa >> 7) & 1) * 64 + (pa & 63);
      const unsigned short* g;
      if (MODE == 0) {
        g = Ag + (size_t)(n0 + bx * 256 + m) * Dd + kt * 64 + tcs;
      } else {
        g = Ag + (size_t)ez * ncRows * Hd + (size_t)(bx * 256 + m) * Hd + kt * 64 + tcs;
      }
      gload16(g, &As[(size_t)buf * 16384 + (size_t)(mh * 128 + s * 64) * 64 + wid * 512]);
    }
  };
  auto stageB = [&](int buf, int kt, int nh) {
    #pragma unroll
    for (int s = 0; s < 2; ++s) {
      const int pb = nh * 128 + s * 64 + trow;
      const int n = ((pb >> 5) & 3) * 64 + ((pb >> 7) & 1) * 32 + (pb & 31);
      const unsigned short* g;
      if (MODE == 0) {
        g = Bg + (size_t)ez * Hd * Dd + (size_t)(by * 256 + n) * Dd + kt * 64 + tcs;
      } else {
        g = Bg + (size_t)ez * Od * Hd + (size_t)(by * 256 + n) * Hd + kt * 64 + tcs;
      }
      gload16(g, &Bs[(size_t)buf * 16384 + (size_t)(nh * 128 + s * 64) * 64 + wid * 512]);
    }
  };

  const int laneRow = lane & 15;
  const int swzc[2] = { ((lane >> 4) ^ (lane & 7)) << 3,
                        (((lane >> 4) + 4) ^ (lane & 7)) << 3 };
  const int aRowBase = (wm * 64 + laneRow) * 64;
  const int bRowBase = (wn * 32 + laneRow) * 64;

  auto rdA = [&](int buf, int mh, int mi, int kk) -> bf16x8 {
    const int addr = buf * 16384 + aRowBase + (mh * 128 + mi * 16) * 64 + swzc[kk];
    return *(const bf16x8*)&As[addr];
  };
  auto rdB = [&](int buf, int nh, int ni, int kk) -> bf16x8 {
    const int addr = buf * 16384 + bRowBase + (nh * 128 + ni * 16) * 64 + swzc[kk];
    return *(const bf16x8*)&Bs[addr];
  };

  f32x4 acc[8][4];
  #pragma unroll
  for (int i = 0; i < 8; ++i)
    #pragma unroll
    for (int j = 0; j < 4; ++j) acc[i][j] = (f32x4){0.f, 0.f, 0.f, 0.f};
  bf16x8 a0[4][2], a1[4][2], b0[2][2], b1[2][2];

  // prologue: tile0 fully, tile1's B-nh0 + A-mh1; allow 2 newest units outstanding
  stageB(0, 0, 0); stageA(0, 0, 1); stageA(0, 0, 0); stageB(0, 0, 1);
  stageB(1, 1, 0); stageA(1, 1, 1);
  asm volatile("s_waitcnt vmcnt(4)" ::: "memory");
  __builtin_amdgcn_sched_barrier(0);
  __builtin_amdgcn_s_barrier();

  for (int U = 0; U < NT; ++U) {
    const int buf = U & 1, nbuf = buf ^ 1;
    // ---- q0: (mh0, nh0); stage A-mh0 of U+1
    #pragma unroll
    for (int mi = 0; mi < 4; ++mi) { a0[mi][0] = rdA(buf, 0, mi, 0); a0[mi][1] = rdA(buf, 0, mi, 1); }
    #pragma unroll
    for (int ni = 0; ni < 2; ++ni) { b0[ni][0] = rdB(buf, 0, ni, 0); b0[ni][1] = rdB(buf, 0, ni, 1); }
    if (U + 1 < NT) stageA(nbuf, U + 1, 0);
    __builtin_amdgcn_s_barrier();
    LGKM0;
    __builtin_amdgcn_s_setprio(1);
    #pragma unroll
    for (int mi = 0; mi < 4; ++mi)
      #pragma unroll
      for (int ni = 0; ni < 2; ++ni) {
        acc[mi][ni] = __builtin_amdgcn_mfma_f32_16x16x32_bf16(a0[mi][0], b0[ni][0], acc[mi][ni], 0, 0, 0);
        acc[mi][ni] = __builtin_amdgcn_mfma_f32_16x16x32_bf16(a0[mi][1], b0[ni][1], acc[mi][ni], 0, 0, 0);
      }
    __builtin_amdgcn_s_setprio(0);
    __builtin_amdgcn_s_barrier();
    // ---- q1: (mh1, nh0); stage B-nh1 of U+1
    #pragma unroll
    for (int mi = 0; mi < 4; ++mi) { a1[mi][0] = rdA(buf, 1, mi, 0); a1[mi][1] = rdA(buf, 1, mi, 1); }
    if (U + 1 < NT) stageB(nbuf, U + 1, 1);
    __builtin_amdgcn_s_barrier();
    LGKM0;
    __builtin_amdgcn_s_setprio(1);
    #pragma unroll
    for (int mi = 0; mi < 4; ++mi)
      #pragma unroll
      for (int ni = 0; ni < 2; ++ni) {
        acc[4 + mi][ni] = __builtin_amdgcn_mfma_f32_16x16x32_bf16(a1[mi][0], b0[ni][0], acc[4 + mi][ni], 0, 0, 0);
        acc[4 + mi][ni] = __builtin_amdgcn_mfma_f32_16x16x32_bf16(a1[mi][1], b0[ni][1], acc[4 + mi][ni], 0, 0, 0);
      }
    __builtin_amdgcn_s_setprio(0);
    __builtin_amdgcn_s_barrier();
    // ---- q2: (mh1, nh1); stage B-nh0 of U+2 (region last read at q0)
    #pragma unroll
    for (int ni = 0; ni < 2; ++ni) { b1[ni][0] = rdB(buf, 1, ni, 0); b1[ni][1] = rdB(buf, 1, ni, 1); }
    if (U + 2 < NT) stageB(buf, U + 2, 0);
    __builtin_amdgcn_s_barrier();
    LGKM0;
    __builtin_amdgcn_s_setprio(1);
    #pragma unroll
    for (int mi = 0; mi < 4; ++mi)
      #pragma unroll
      for (int ni = 0; ni < 2; ++ni) {
        acc[4 + mi][2 + ni] = __builtin_amdgcn_mfma_f32_16x16x32_bf16(a1[mi][0], b1[ni][0], acc[4 + mi][2 + ni], 0, 0, 0);
        acc[4 + mi][2 + ni] = __builtin_amdgcn_mfma_f32_16x16x32_bf16(a1[mi][1], b1[ni][1], acc[4 + mi][2 + ni], 0, 0, 0);
      }
    __builtin_amdgcn_s_setprio(0);
    __builtin_amdgcn_s_barrier();
    // ---- q3: (mh0, nh1) [no ds_reads]; stage A-mh1 of U+2 (last read at q1)
    if (U + 2 < NT) stageA(buf, U + 2, 1);
    __builtin_amdgcn_s_barrier();
    __builtin_amdgcn_s_setprio(1);
    #pragma unroll
    for (int mi = 0; mi < 4; ++mi)
      #pragma unroll
      for (int ni = 0; ni < 2; ++ni) {
        acc[mi][2 + ni] = __builtin_amdgcn_mfma_f32_16x16x32_bf16(a0[mi][0], b1[ni][0], acc[mi][2 + ni], 0, 0, 0);
        acc[mi][2 + ni] = __builtin_amdgcn_mfma_f32_16x16x32_bf16(a0[mi][1], b1[ni][1], acc[mi][2 + ni], 0, 0, 0);
      }
    __builtin_amdgcn_s_setprio(0);
    // boundary: ensure tile U+1 resident; 4 loads (q2+q3 stages) may remain in flight
    if (U + 2 < NT) {
      asm volatile("s_waitcnt vmcnt(4)" ::: "memory");
    } else if (U + 1 < NT) {
      asm volatile("s_waitcnt vmcnt(0)" ::: "memory");
    }
    __builtin_amdgcn_sched_barrier(0);
    __builtin_amdgcn_s_barrier();
  }

  // ---------------- epilogue ----------------
  if (MODE == 0) {
    unsigned short* hs = (unsigned short*)Cout;
    unsigned short* base = hs + (size_t)ez * ((size_t)ncRows * Hd);
    #pragma unroll
    for (int M = 0; M < 8; ++M) {
      const int mh = M >> 2, mi = M & 3;
      const int row = bx * 256 + wm * 128 + mh * 64 + mi * 16 + (lane >> 4) * 4;
      float rw[4];
      #pragma unroll
      for (int j = 0; j < 4; ++j) rw[j] = route[(size_t)(n0 + row + j) * Ed + ez];
      #pragma unroll
      for (int N = 0; N < 4; ++N) {
        const int nh = N >> 1, ni = N & 1;
        const int col = by * 256 + wn * 64 + nh * 32 + ni * 16 + (lane & 15);
        const float bv = bias[ez * Hd + col];
        #pragma unroll
        for (int j = 0; j < 4; ++j) {
          float v = acc[M][N][j] + bv;
          v = fmaxf(v, 0.f);
          v = v * v * rw[j];
          base[(size_t)(row + j) * Hd + col] = f2bf(v);
        }
      }
    }
  } else {
    float* out = (float*)Cout;
    #pragma unroll
    for (int M = 0; M < 8; ++M) {
      const int mh = M >> 2, mi = M & 3;
      const int row = n0 + bx * 256 + wm * 128 + mh * 64 + mi * 16 + (lane >> 4) * 4;
      #pragma unroll
      for (int N = 0; N < 4; ++N) {
        const int nh = N >> 1, ni = N & 1;
        const int col = by * 256 + wn * 64 + nh * 32 + ni * 16 + (lane & 15);
        #pragma unroll
        for (int j = 0; j < 4; ++j)
          atomicAdd(out + (size_t)(row + j) * Od + col, acc[M][N][j]);
      }
    }
  }
}

extern "C" void kernel_launch(void* const* d_in, const int* in_sizes, int n_in,
                              void* d_out, int out_size, void* d_ws, size_t ws_size,
                              hipStream_t stream) {
  const float* x  = (const float*)d_in[0];
  const float* Wr = (const float*)d_in[1];
  const float* br = (const float*)d_in[2];
  const float* W1 = (const float*)d_in[3];
  const float* b1 = (const float*)d_in[4];
  const float* W2 = (const float*)d_in[5];
  const float* b2 = (const float*)d_in[6];
  float* out = (float*)d_out;

  char* ws = (char*)d_ws;
  size_t off = 0;
  float* route = (float*)(ws + off);                 off += (size_t)Nd * Ed * 4;
  unsigned short* xb  = (unsigned short*)(ws + off); off += (size_t)Nd * Dd * 2;
  unsigned short* w1b = (unsigned short*)(ws + off); off += (size_t)Ed * Hd * Dd * 2;
  unsigned short* w2b = (unsigned short*)(ws + off); off += (size_t)Ed * Od * Hd * 2;
  unsigned short* hs  = (unsigned short*)(ws + off);

  size_t remain = (ws_size > off) ? (ws_size - off) : 0;
  const size_t perRow = (size_t)Ed * Hd * 2;  // bytes of hs per token row
  long long ncMax = (long long)(remain / perRow);
  int NC = (int)(ncMax & ~255LL);
  if (NC > 2048) NC = 2048;   // cap: keep hs chunk (67 MB) L3-resident
  if (NC < 256) NC = 256;

  hipFuncSetAttribute(reinterpret_cast<const void*>(&gemm8p<0>),
                      hipFuncAttributeMaxDynamicSharedMemorySize, 131072);
  hipFuncSetAttribute(reinterpret_cast<const void*>(&gemm8p<1>),
                      hipFuncAttributeMaxDynamicSharedMemorySize, 131072);

  cvt_kernel<<<2048, 256, 0, stream>>>(W1, w1b, Ed * Hd * Dd / 8);
  cvt_kernel<<<2048, 256, 0, stream>>>(W2, w2b, Ed * Od * Hd / 8);
  router_kernel<<<Nd, 256, 0, stream>>>(x, Wr, br, route, xb);
  init_out_kernel<<<Nd * Od / 256, 256, 0, stream>>>(route, b2, out);

  for (int n0 = 0; n0 < Nd; n0 += NC) {
    int nc = (NC < (Nd - n0)) ? NC : (Nd - n0);
    int ngx = nc / 256;
    gemm8p<0><<<ngx * 8 * Ed, 512, 131072, stream>>>(xb, w1b, b1, route, hs, n0, nc, ngx);
    gemm8p<1><<<ngx * 4 * Ed, 512, 131072, stream>>>(hs, w2b, nullptr, nullptr, out, n0, nc, ngx);
  }
}

// Round 5
// 367.722 us; speedup vs baseline: 1.1607x; 1.1057x over previous
//
#include <hip/hip_runtime.h>
#include <hip/hip_bf16.h>
#include <stdint.h>

#define Dd 1024
#define Hd 2048
#define Od 1024
#define Ed 8
#define Nd 4096

typedef __bf16 bf16x8 __attribute__((ext_vector_type(8)));
typedef float f32x4 __attribute__((ext_vector_type(4)));

__device__ __forceinline__ void gload16(const void* g, void* l) {
  __builtin_amdgcn_global_load_lds(
      (const __attribute__((address_space(1))) void*)g,
      (__attribute__((address_space(3))) void*)l, 16, 0, 0);
}

__device__ __forceinline__ unsigned short f2bf(float f) {
  __hip_bfloat16 h = __float2bfloat16(f);
  return *reinterpret_cast<unsigned short*>(&h);
}

// ---------- f32 -> bf16 conversion, 8 elems / thread ----------
__global__ void cvt_kernel(const float* __restrict__ in,
                           unsigned short* __restrict__ out, int ngroups) {
  int stride = gridDim.x * blockDim.x;
  for (int g = blockIdx.x * blockDim.x + threadIdx.x; g < ngroups; g += stride) {
    const float4* p = (const float4*)(in + (size_t)g * 8);
    float4 a = p[0], b = p[1];
    unsigned short o[8];
    o[0] = f2bf(a.x); o[1] = f2bf(a.y); o[2] = f2bf(a.z); o[3] = f2bf(a.w);
    o[4] = f2bf(b.x); o[5] = f2bf(b.y); o[6] = f2bf(b.z); o[7] = f2bf(b.w);
    *(int4*)(out + (size_t)g * 8) = *(int4*)o;
  }
}

// ---------- router (also emits xb bf16) ----------
__global__ void router_kernel(const float* __restrict__ x, const float* __restrict__ Wr,
                              const float* __restrict__ br, float* __restrict__ route,
                              unsigned short* __restrict__ xb) {
  const int n = blockIdx.x;
  const int t = threadIdx.x;  // 256
  __shared__ float xs[Dd];
  float4 v = *(const float4*)&x[(size_t)n * Dd + t * 4];
  *(float4*)&xs[t * 4] = v;
  unsigned short o[4] = {f2bf(v.x), f2bf(v.y), f2bf(v.z), f2bf(v.w)};
  *(uint2*)&xb[(size_t)n * Dd + t * 4] = *(const uint2*)o;
  __syncthreads();
  float p[Ed];
  #pragma unroll
  for (int e = 0; e < Ed; ++e) p[e] = 0.f;
  for (int d = t; d < Dd; d += 256) {
    float xv = xs[d];
    #pragma unroll
    for (int e = 0; e < Ed; ++e) p[e] += xv * Wr[e * Dd + d];
  }
  __shared__ float red[Ed][4];
  const int lane = t & 63, wid = t >> 6;
  #pragma unroll
  for (int e = 0; e < Ed; ++e) {
    float vv = p[e];
    for (int off = 32; off > 0; off >>= 1) vv += __shfl_down(vv, off);
    if (lane == 0) red[e][wid] = vv;
  }
  __syncthreads();
  if (t == 0) {
    float lg[Ed], mx = -1e30f;
    #pragma unroll
    for (int e = 0; e < Ed; ++e) {
      lg[e] = red[e][0] + red[e][1] + red[e][2] + red[e][3] + br[e];
      mx = fmaxf(mx, lg[e]);
    }
    float s = 0.f;
    #pragma unroll
    for (int e = 0; e < Ed; ++e) { lg[e] = expf(lg[e] - mx); s += lg[e]; }
    float inv = 1.f / s;
    #pragma unroll
    for (int e = 0; e < Ed; ++e) route[(size_t)n * Ed + e] = lg[e] * inv;
  }
}

// ---------- out init: out[n,o] = sum_e route[n,e] * b2[e,o] ----------
__global__ void init_out_kernel(const float* __restrict__ route, const float* __restrict__ b2,
                                float* __restrict__ out) {
  const int idx = blockIdx.x * 256 + threadIdx.x;
  const int n = idx >> 10, o = idx & (Od - 1);
  float s = 0.f;
  #pragma unroll
  for (int e = 0; e < Ed; ++e) s += route[(size_t)n * Ed + e] * b2[e * Od + o];
  out[idx] = s;
}

#define LGKM0 do { asm volatile("s_waitcnt lgkmcnt(0)" ::: "memory"); \
                   __builtin_amdgcn_sched_barrier(0); } while (0)

// ============ 256x256 4-phase GEMM (MODE 0 = gemm1, 1 = gemm2) ============
// R2's mixed-depth prefetch ledger, single barrier per phase (post-MFMA):
//   q0 stages A-mh0(U+1)->nbuf ; q1 stages B-nh1(U+1)->nbuf ;
//   q2 stages B-nh0(U+2)->buf  ; q3 stages A-mh1(U+2)->buf ;
//   boundary vmcnt(4) keeps the 4 newest (U+2's) per-wave loads in flight.
// Race-freedom: the post-MFMA barrier of phase p guarantees all waves'
// ds_reads of phase p completed (each wave lgkm0's before its MFMA) before
// any wave's later stage-DMA targets that region; DMA-write vs ds_read
// hazards are mediated by the boundary vmcnt+barrier (unchanged).
// MODE 1 is 2-expert z-pair (ez in [0,4)), NT=64, atomics into out.
template <int MODE>
__global__ __launch_bounds__(512, 2) void gemm8p(
    const unsigned short* __restrict__ Ag,
    const unsigned short* __restrict__ Bg,
    const float* __restrict__ bias,
    const float* __restrict__ route,
    void* __restrict__ Cout,
    int n0, int ncRows, int ngx) {
  extern __shared__ unsigned short smem[];
  unsigned short* As = smem;            // 2 x 16384
  unsigned short* Bs = smem + 32768;    // 2 x 16384

  // bijective XCD swizzle (nwg % 8 == 0 by construction)
  const int nwg = gridDim.x;
  const int orig = blockIdx.x;
  const int q8 = nwg >> 3;
  const int wg = (orig & 7) * q8 + (orig >> 3);
  const int bx = wg % ngx;
  const int rem = wg / ngx;
  int by, ez;
  if (MODE == 0) { by = rem & 7; ez = rem >> 3; }       // by in [0,8), expert in [0,8)
  else           { by = rem & 3; ez = rem >> 2; }       // by in [0,4), z-pair in [0,4)

  const int tid = threadIdx.x;
  const int wid = tid >> 6, lane = tid & 63;
  const int wm = wid >> 2, wn = wid & 3;

  const int trow = tid >> 3;                       // row-within-strip for staging
  const int tcs = ((tid & 7) ^ (trow & 7)) * 8;    // inverse-swizzled source col (elems)

  const int NT = (MODE == 0) ? (Dd / 64) : (2 * Hd / 64);

  auto stageA = [&](int buf, int kt, int mh) {
    #pragma unroll
    for (int s = 0; s < 2; ++s) {
      const int pa = mh * 128 + s * 64 + trow;
      const int m = ((pa >> 6) & 1) * 128 + ((pa >> 7) & 1) * 64 + (pa & 63);
      const unsigned short* g;
      if (MODE == 0) {
        g = Ag + (size_t)(n0 + bx * 256 + m) * Dd + kt * 64 + tcs;
      } else {
        const int e = ez * 2 + (kt >> 5);
        g = Ag + (size_t)e * ncRows * Hd + (size_t)(bx * 256 + m) * Hd + (kt & 31) * 64 + tcs;
      }
      gload16(g, &As[(size_t)buf * 16384 + (size_t)(mh * 128 + s * 64) * 64 + wid * 512]);
    }
  };
  auto stageB = [&](int buf, int kt, int nh) {
    #pragma unroll
    for (int s = 0; s < 2; ++s) {
      const int pb = nh * 128 + s * 64 + trow;
      const int n = ((pb >> 5) & 3) * 64 + ((pb >> 7) & 1) * 32 + (pb & 31);
      const unsigned short* g;
      if (MODE == 0) {
        g = Bg + (size_t)ez * Hd * Dd + (size_t)(by * 256 + n) * Dd + kt * 64 + tcs;
      } else {
        const int e = ez * 2 + (kt >> 5);
        g = Bg + (size_t)e * Od * Hd + (size_t)(by * 256 + n) * Hd + (kt & 31) * 64 + tcs;
      }
      gload16(g, &Bs[(size_t)buf * 16384 + (size_t)(nh * 128 + s * 64) * 64 + wid * 512]);
    }
  };

  const int laneRow = lane & 15;
  const int swzc[2] = { ((lane >> 4) ^ (lane & 7)) << 3,
                        (((lane >> 4) + 4) ^ (lane & 7)) << 3 };
  const int aRowBase = (wm * 64 + laneRow) * 64;
  const int bRowBase = (wn * 32 + laneRow) * 64;

  auto rdA = [&](int buf, int mh, int mi, int kk) -> bf16x8 {
    const int addr = buf * 16384 + aRowBase + (mh * 128 + mi * 16) * 64 + swzc[kk];
    return *(const bf16x8*)&As[addr];
  };
  auto rdB = [&](int buf, int nh, int ni, int kk) -> bf16x8 {
    const int addr = buf * 16384 + bRowBase + (nh * 128 + ni * 16) * 64 + swzc[kk];
    return *(const bf16x8*)&Bs[addr];
  };

  f32x4 acc[8][4];
  #pragma unroll
  for (int i = 0; i < 8; ++i)
    #pragma unroll
    for (int j = 0; j < 4; ++j) acc[i][j] = (f32x4){0.f, 0.f, 0.f, 0.f};
  bf16x8 a0[4][2], a1[4][2], b0[2][2], b1[2][2];

  // prologue: tile0 fully, tile1's B-nh0 + A-mh1; allow 2 newest units outstanding
  stageB(0, 0, 0); stageA(0, 0, 1); stageA(0, 0, 0); stageB(0, 0, 1);
  stageB(1, 1, 0); stageA(1, 1, 1);
  asm volatile("s_waitcnt vmcnt(4)" ::: "memory");
  __builtin_amdgcn_sched_barrier(0);
  __builtin_amdgcn_s_barrier();

  for (int U = 0; U < NT; ++U) {
    const int buf = U & 1, nbuf = buf ^ 1;
    // ---- q0: (mh0, nh0); stage A-mh0 of U+1
    #pragma unroll
    for (int mi = 0; mi < 4; ++mi) { a0[mi][0] = rdA(buf, 0, mi, 0); a0[mi][1] = rdA(buf, 0, mi, 1); }
    #pragma unroll
    for (int ni = 0; ni < 2; ++ni) { b0[ni][0] = rdB(buf, 0, ni, 0); b0[ni][1] = rdB(buf, 0, ni, 1); }
    if (U + 1 < NT) stageA(nbuf, U + 1, 0);
    LGKM0;
    __builtin_amdgcn_s_setprio(1);
    #pragma unroll
    for (int mi = 0; mi < 4; ++mi)
      #pragma unroll
      for (int ni = 0; ni < 2; ++ni) {
        acc[mi][ni] = __builtin_amdgcn_mfma_f32_16x16x32_bf16(a0[mi][0], b0[ni][0], acc[mi][ni], 0, 0, 0);
        acc[mi][ni] = __builtin_amdgcn_mfma_f32_16x16x32_bf16(a0[mi][1], b0[ni][1], acc[mi][ni], 0, 0, 0);
      }
    __builtin_amdgcn_s_setprio(0);
    __builtin_amdgcn_s_barrier();
    // ---- q1: (mh1, nh0); stage B-nh1 of U+1
    #pragma unroll
    for (int mi = 0; mi < 4; ++mi) { a1[mi][0] = rdA(buf, 1, mi, 0); a1[mi][1] = rdA(buf, 1, mi, 1); }
    if (U + 1 < NT) stageB(nbuf, U + 1, 1);
    LGKM0;
    __builtin_amdgcn_s_setprio(1);
    #pragma unroll
    for (int mi = 0; mi < 4; ++mi)
      #pragma unroll
      for (int ni = 0; ni < 2; ++ni) {
        acc[4 + mi][ni] = __builtin_amdgcn_mfma_f32_16x16x32_bf16(a1[mi][0], b0[ni][0], acc[4 + mi][ni], 0, 0, 0);
        acc[4 + mi][ni] = __builtin_amdgcn_mfma_f32_16x16x32_bf16(a1[mi][1], b0[ni][1], acc[4 + mi][ni], 0, 0, 0);
      }
    __builtin_amdgcn_s_setprio(0);
    __builtin_amdgcn_s_barrier();
    // ---- q2: (mh1, nh1); stage B-nh0 of U+2 (region last read at q0)
    #pragma unroll
    for (int ni = 0; ni < 2; ++ni) { b1[ni][0] = rdB(buf, 1, ni, 0); b1[ni][1] = rdB(buf, 1, ni, 1); }
    if (U + 2 < NT) stageB(buf, U + 2, 0);
    LGKM0;
    __builtin_amdgcn_s_setprio(1);
    #pragma unroll
    for (int mi = 0; mi < 4; ++mi)
      #pragma unroll
      for (int ni = 0; ni < 2; ++ni) {
        acc[4 + mi][2 + ni] = __builtin_amdgcn_mfma_f32_16x16x32_bf16(a1[mi][0], b1[ni][0], acc[4 + mi][2 + ni], 0, 0, 0);
        acc[4 + mi][2 + ni] = __builtin_amdgcn_mfma_f32_16x16x32_bf16(a1[mi][1], b1[ni][1], acc[4 + mi][2 + ni], 0, 0, 0);
      }
    __builtin_amdgcn_s_setprio(0);
    __builtin_amdgcn_s_barrier();
    // ---- q3: (mh0, nh1) [no ds_reads]; stage A-mh1 of U+2 (last read at q1)
    if (U + 2 < NT) stageA(buf, U + 2, 1);
    __builtin_amdgcn_s_setprio(1);
    #pragma unroll
    for (int mi = 0; mi < 4; ++mi)
      #pragma unroll
      for (int ni = 0; ni < 2; ++ni) {
        acc[mi][2 + ni] = __builtin_amdgcn_mfma_f32_16x16x32_bf16(a0[mi][0], b1[ni][0], acc[mi][2 + ni], 0, 0, 0);
        acc[mi][2 + ni] = __builtin_amdgcn_mfma_f32_16x16x32_bf16(a0[mi][1], b1[ni][1], acc[mi][2 + ni], 0, 0, 0);
      }
    __builtin_amdgcn_s_setprio(0);
    // boundary: ensure tile U+1 resident; 4 loads (q2+q3 stages) may remain in flight
    if (U + 2 < NT) {
      asm volatile("s_waitcnt vmcnt(4)" ::: "memory");
    } else if (U + 1 < NT) {
      asm volatile("s_waitcnt vmcnt(0)" ::: "memory");
    }
    __builtin_amdgcn_sched_barrier(0);
    __builtin_amdgcn_s_barrier();
  }

  // ---------------- epilogue ----------------
  if (MODE == 0) {
    unsigned short* hs = (unsigned short*)Cout;
    unsigned short* base = hs + (size_t)ez * ((size_t)ncRows * Hd);
    #pragma unroll
    for (int M = 0; M < 8; ++M) {
      const int mh = M >> 2, mi = M & 3;
      const int row = bx * 256 + wm * 128 + mh * 64 + mi * 16 + (lane >> 4) * 4;
      float rw[4];
      #pragma unroll
      for (int j = 0; j < 4; ++j) rw[j] = route[(size_t)(n0 + row + j) * Ed + ez];
      #pragma unroll
      for (int N = 0; N < 4; ++N) {
        const int nh = N >> 1, ni = N & 1;
        const int col = by * 256 + wn * 64 + nh * 32 + ni * 16 + (lane & 15);
        const float bv = bias[ez * Hd + col];
        #pragma unroll
        for (int j = 0; j < 4; ++j) {
          float v = acc[M][N][j] + bv;
          v = fmaxf(v, 0.f);
          v = v * v * rw[j];
          base[(size_t)(row + j) * Hd + col] = f2bf(v);
        }
      }
    }
  } else {
    float* out = (float*)Cout;
    #pragma unroll
    for (int M = 0; M < 8; ++M) {
      const int mh = M >> 2, mi = M & 3;
      const int row = n0 + bx * 256 + wm * 128 + mh * 64 + mi * 16 + (lane >> 4) * 4;
      #pragma unroll
      for (int N = 0; N < 4; ++N) {
        const int nh = N >> 1, ni = N & 1;
        const int col = by * 256 + wn * 64 + nh * 32 + ni * 16 + (lane & 15);
        #pragma unroll
        for (int j = 0; j < 4; ++j)
          atomicAdd(out + (size_t)(row + j) * Od + col, acc[M][N][j]);
      }
    }
  }
}

extern "C" void kernel_launch(void* const* d_in, const int* in_sizes, int n_in,
                              void* d_out, int out_size, void* d_ws, size_t ws_size,
                              hipStream_t stream) {
  const float* x  = (const float*)d_in[0];
  const float* Wr = (const float*)d_in[1];
  const float* br = (const float*)d_in[2];
  const float* W1 = (const float*)d_in[3];
  const float* b1 = (const float*)d_in[4];
  const float* W2 = (const float*)d_in[5];
  const float* b2 = (const float*)d_in[6];
  float* out = (float*)d_out;

  char* ws = (char*)d_ws;
  size_t off = 0;
  float* route = (float*)(ws + off);                 off += (size_t)Nd * Ed * 4;
  unsigned short* xb  = (unsigned short*)(ws + off); off += (size_t)Nd * Dd * 2;
  unsigned short* w1b = (unsigned short*)(ws + off); off += (size_t)Ed * Hd * Dd * 2;
  unsigned short* w2b = (unsigned short*)(ws + off); off += (size_t)Ed * Od * Hd * 2;
  unsigned short* hs  = (unsigned short*)(ws + off);

  size_t remain = (ws_size > off) ? (ws_size - off) : 0;
  const size_t perRow = (size_t)Ed * Hd * 2;  // bytes of hs per token row
  long long ncMax = (long long)(remain / perRow);
  int NC = (int)(ncMax & ~255LL);
  if (NC > Nd) NC = Nd;
  if (NC < 256) NC = 256;

  hipFuncSetAttribute(reinterpret_cast<const void*>(&gemm8p<0>),
                      hipFuncAttributeMaxDynamicSharedMemorySize, 131072);
  hipFuncSetAttribute(reinterpret_cast<const void*>(&gemm8p<1>),
                      hipFuncAttributeMaxDynamicSharedMemorySize, 131072);

  cvt_kernel<<<2048, 256, 0, stream>>>(W1, w1b, Ed * Hd * Dd / 8);
  cvt_kernel<<<2048, 256, 0, stream>>>(W2, w2b, Ed * Od * Hd / 8);
  router_kernel<<<Nd, 256, 0, stream>>>(x, Wr, br, route, xb);
  init_out_kernel<<<Nd * Od / 256, 256, 0, stream>>>(route, b2, out);

  for (int n0 = 0; n0 < Nd; n0 += NC) {
    int nc = (NC < (Nd - n0)) ? NC : (Nd - n0);
    int ngx = nc / 256;
    gemm8p<0><<<ngx * 8 * Ed, 512, 131072, stream>>>(xb, w1b, b1, route, hs, n0, nc, ngx);
    gemm8p<1><<<ngx * 4 * 4, 512, 131072, stream>>>(hs, w2b, nullptr, nullptr, out, n0, nc, ngx);
  }
}

// Round 6
// 361.071 us; speedup vs baseline: 1.1821x; 1.0184x over previous
//
#include <hip/hip_runtime.h>
#include <hip/hip_bf16.h>
#include <stdint.h>

#define Dd 1024
#define Hd 2048
#define Od 1024
#define Ed 8
#define Nd 4096

typedef __bf16 bf16x8 __attribute__((ext_vector_type(8)));
typedef float f32x4 __attribute__((ext_vector_type(4)));

__device__ __forceinline__ void gload16(const void* g, void* l) {
  __builtin_amdgcn_global_load_lds(
      (const __attribute__((address_space(1))) void*)g,
      (__attribute__((address_space(3))) void*)l, 16, 0, 0);
}

__device__ __forceinline__ unsigned short f2bf(float f) {
  __hip_bfloat16 h = __float2bfloat16(f);
  return *reinterpret_cast<unsigned short*>(&h);
}

// ---------- f32 -> bf16 conversion, 8 elems / thread ----------
__global__ void cvt_kernel(const float* __restrict__ in,
                           unsigned short* __restrict__ out, int ngroups) {
  int stride = gridDim.x * blockDim.x;
  for (int g = blockIdx.x * blockDim.x + threadIdx.x; g < ngroups; g += stride) {
    const float4* p = (const float4*)(in + (size_t)g * 8);
    float4 a = p[0], b = p[1];
    unsigned short o[8];
    o[0] = f2bf(a.x); o[1] = f2bf(a.y); o[2] = f2bf(a.z); o[3] = f2bf(a.w);
    o[4] = f2bf(b.x); o[5] = f2bf(b.y); o[6] = f2bf(b.z); o[7] = f2bf(b.w);
    *(int4*)(out + (size_t)g * 8) = *(int4*)o;
  }
}

// ---------- router (also emits xb bf16) ----------
__global__ void router_kernel(const float* __restrict__ x, const float* __restrict__ Wr,
                              const float* __restrict__ br, float* __restrict__ route,
                              unsigned short* __restrict__ xb) {
  const int n = blockIdx.x;
  const int t = threadIdx.x;  // 256
  __shared__ float xs[Dd];
  float4 v = *(const float4*)&x[(size_t)n * Dd + t * 4];
  *(float4*)&xs[t * 4] = v;
  unsigned short o[4] = {f2bf(v.x), f2bf(v.y), f2bf(v.z), f2bf(v.w)};
  *(uint2*)&xb[(size_t)n * Dd + t * 4] = *(const uint2*)o;
  __syncthreads();
  float p[Ed];
  #pragma unroll
  for (int e = 0; e < Ed; ++e) p[e] = 0.f;
  for (int d = t; d < Dd; d += 256) {
    float xv = xs[d];
    #pragma unroll
    for (int e = 0; e < Ed; ++e) p[e] += xv * Wr[e * Dd + d];
  }
  __shared__ float red[Ed][4];
  const int lane = t & 63, wid = t >> 6;
  #pragma unroll
  for (int e = 0; e < Ed; ++e) {
    float vv = p[e];
    for (int off = 32; off > 0; off >>= 1) vv += __shfl_down(vv, off);
    if (lane == 0) red[e][wid] = vv;
  }
  __syncthreads();
  if (t == 0) {
    float lg[Ed], mx = -1e30f;
    #pragma unroll
    for (int e = 0; e < Ed; ++e) {
      lg[e] = red[e][0] + red[e][1] + red[e][2] + red[e][3] + br[e];
      mx = fmaxf(mx, lg[e]);
    }
    float s = 0.f;
    #pragma unroll
    for (int e = 0; e < Ed; ++e) { lg[e] = expf(lg[e] - mx); s += lg[e]; }
    float inv = 1.f / s;
    #pragma unroll
    for (int e = 0; e < Ed; ++e) route[(size_t)n * Ed + e] = lg[e] * inv;
  }
}

// ---------- out init: out[n,o] = sum_e route[n,e] * b2[e,o] ----------
__global__ void init_out_kernel(const float* __restrict__ route, const float* __restrict__ b2,
                                float* __restrict__ out) {
  const int idx = blockIdx.x * 256 + threadIdx.x;
  const int n = idx >> 10, o = idx & (Od - 1);
  float s = 0.f;
  #pragma unroll
  for (int e = 0; e < Ed; ++e) s += route[(size_t)n * Ed + e] * b2[e * Od + o];
  out[idx] = s;
}

// ============ 256x256 4-phase GEMM (MODE 0 = gemm1, 1 = gemm2) ============
// R5 structure, but with NO per-phase lgkmcnt/sched_barrier pins: ds_reads are
// compiler-visible loads feeding MFMA intrinsics, so the compiler inserts its
// own fine-grained counted lgkm waits and may interleave read-completion with
// MFMA issue (m97 evidence; m141 showed order-pinning costs ~40%).
// Pins remain ONLY at tile boundaries (DMA->read hand-off), where the
// compiler cannot see the dependency through global_load_lds:
//   boundary = s_waitcnt vmcnt(N) + sched_barrier(0) + s_barrier.
// Ledger (unchanged from R2/R5):
//   q0 stages A-mh0(U+1)->nbuf ; q1 stages B-nh1(U+1)->nbuf ;
//   q2 stages B-nh0(U+2)->buf  ; q3 stages A-mh1(U+2)->buf ;
//   boundary vmcnt(4) keeps the 4 newest (U+2's) per-wave loads in flight.
// Race-freedom: per-phase post-MFMA barrier still orders every wave's phase-p
// ds_read completion (enforced by the compiler's own waits before MFMA)
// ahead of any later DMA issue into that region.
template <int MODE>
__global__ __launch_bounds__(512, 2) void gemm8p(
    const unsigned short* __restrict__ Ag,
    const unsigned short* __restrict__ Bg,
    const float* __restrict__ bias,
    const float* __restrict__ route,
    void* __restrict__ Cout,
    int n0, int ncRows, int ngx) {
  extern __shared__ unsigned short smem[];
  unsigned short* As = smem;            // 2 x 16384
  unsigned short* Bs = smem + 32768;    // 2 x 16384

  // bijective XCD swizzle (nwg % 8 == 0 by construction)
  const int nwg = gridDim.x;
  const int orig = blockIdx.x;
  const int q8 = nwg >> 3;
  const int wg = (orig & 7) * q8 + (orig >> 3);
  const int bx = wg % ngx;
  const int rem = wg / ngx;
  int by, ez;
  if (MODE == 0) { by = rem & 7; ez = rem >> 3; }       // by in [0,8), expert in [0,8)
  else           { by = rem & 3; ez = rem >> 2; }       // by in [0,4), z-pair in [0,4)

  const int tid = threadIdx.x;
  const int wid = tid >> 6, lane = tid & 63;
  const int wm = wid >> 2, wn = wid & 3;

  const int trow = tid >> 3;                       // row-within-strip for staging
  const int tcs = ((tid & 7) ^ (trow & 7)) * 8;    // inverse-swizzled source col (elems)

  const int NT = (MODE == 0) ? (Dd / 64) : (2 * Hd / 64);

  auto stageA = [&](int buf, int kt, int mh) {
    #pragma unroll
    for (int s = 0; s < 2; ++s) {
      const int pa = mh * 128 + s * 64 + trow;
      const int m = ((pa >> 6) & 1) * 128 + ((pa >> 7) & 1) * 64 + (pa & 63);
      const unsigned short* g;
      if (MODE == 0) {
        g = Ag + (size_t)(n0 + bx * 256 + m) * Dd + kt * 64 + tcs;
      } else {
        const int e = ez * 2 + (kt >> 5);
        g = Ag + (size_t)e * ncRows * Hd + (size_t)(bx * 256 + m) * Hd + (kt & 31) * 64 + tcs;
      }
      gload16(g, &As[(size_t)buf * 16384 + (size_t)(mh * 128 + s * 64) * 64 + wid * 512]);
    }
  };
  auto stageB = [&](int buf, int kt, int nh) {
    #pragma unroll
    for (int s = 0; s < 2; ++s) {
      const int pb = nh * 128 + s * 64 + trow;
      const int n = ((pb >> 5) & 3) * 64 + ((pb >> 7) & 1) * 32 + (pb & 31);
      const unsigned short* g;
      if (MODE == 0) {
        g = Bg + (size_t)ez * Hd * Dd + (size_t)(by * 256 + n) * Dd + kt * 64 + tcs;
      } else {
        const int e = ez * 2 + (kt >> 5);
        g = Bg + (size_t)e * Od * Hd + (size_t)(by * 256 + n) * Hd + (kt & 31) * 64 + tcs;
      }
      gload16(g, &Bs[(size_t)buf * 16384 + (size_t)(nh * 128 + s * 64) * 64 + wid * 512]);
    }
  };

  const int laneRow = lane & 15;
  const int swzc[2] = { ((lane >> 4) ^ (lane & 7)) << 3,
                        (((lane >> 4) + 4) ^ (lane & 7)) << 3 };
  const int aRowBase = (wm * 64 + laneRow) * 64;
  const int bRowBase = (wn * 32 + laneRow) * 64;

  auto rdA = [&](int buf, int mh, int mi, int kk) -> bf16x8 {
    const int addr = buf * 16384 + aRowBase + (mh * 128 + mi * 16) * 64 + swzc[kk];
    return *(const bf16x8*)&As[addr];
  };
  auto rdB = [&](int buf, int nh, int ni, int kk) -> bf16x8 {
    const int addr = buf * 16384 + bRowBase + (nh * 128 + ni * 16) * 64 + swzc[kk];
    return *(const bf16x8*)&Bs[addr];
  };

  f32x4 acc[8][4];
  #pragma unroll
  for (int i = 0; i < 8; ++i)
    #pragma unroll
    for (int j = 0; j < 4; ++j) acc[i][j] = (f32x4){0.f, 0.f, 0.f, 0.f};
  bf16x8 a0[4][2], a1[4][2], b0[2][2], b1[2][2];

  // prologue: tile0 fully, tile1's B-nh0 + A-mh1; allow 2 newest units outstanding
  stageB(0, 0, 0); stageA(0, 0, 1); stageA(0, 0, 0); stageB(0, 0, 1);
  stageB(1, 1, 0); stageA(1, 1, 1);
  asm volatile("s_waitcnt vmcnt(4)" ::: "memory");
  __builtin_amdgcn_sched_barrier(0);
  __builtin_amdgcn_s_barrier();

  for (int U = 0; U < NT; ++U) {
    const int buf = U & 1, nbuf = buf ^ 1;
    // ---- q0: (mh0, nh0); stage A-mh0 of U+1
    #pragma unroll
    for (int mi = 0; mi < 4; ++mi) { a0[mi][0] = rdA(buf, 0, mi, 0); a0[mi][1] = rdA(buf, 0, mi, 1); }
    #pragma unroll
    for (int ni = 0; ni < 2; ++ni) { b0[ni][0] = rdB(buf, 0, ni, 0); b0[ni][1] = rdB(buf, 0, ni, 1); }
    if (U + 1 < NT) stageA(nbuf, U + 1, 0);
    __builtin_amdgcn_s_setprio(1);
    #pragma unroll
    for (int mi = 0; mi < 4; ++mi)
      #pragma unroll
      for (int ni = 0; ni < 2; ++ni) {
        acc[mi][ni] = __builtin_amdgcn_mfma_f32_16x16x32_bf16(a0[mi][0], b0[ni][0], acc[mi][ni], 0, 0, 0);
        acc[mi][ni] = __builtin_amdgcn_mfma_f32_16x16x32_bf16(a0[mi][1], b0[ni][1], acc[mi][ni], 0, 0, 0);
      }
    __builtin_amdgcn_s_setprio(0);
    __builtin_amdgcn_s_barrier();
    // ---- q1: (mh1, nh0); stage B-nh1 of U+1
    #pragma unroll
    for (int mi = 0; mi < 4; ++mi) { a1[mi][0] = rdA(buf, 1, mi, 0); a1[mi][1] = rdA(buf, 1, mi, 1); }
    if (U + 1 < NT) stageB(nbuf, U + 1, 1);
    __builtin_amdgcn_s_setprio(1);
    #pragma unroll
    for (int mi = 0; mi < 4; ++mi)
      #pragma unroll
      for (int ni = 0; ni < 2; ++ni) {
        acc[4 + mi][ni] = __builtin_amdgcn_mfma_f32_16x16x32_bf16(a1[mi][0], b0[ni][0], acc[4 + mi][ni], 0, 0, 0);
        acc[4 + mi][ni] = __builtin_amdgcn_mfma_f32_16x16x32_bf16(a1[mi][1], b0[ni][1], acc[4 + mi][ni], 0, 0, 0);
      }
    __builtin_amdgcn_s_setprio(0);
    __builtin_amdgcn_s_barrier();
    // ---- q2: (mh1, nh1); stage B-nh0 of U+2 (region last read at q0)
    #pragma unroll
    for (int ni = 0; ni < 2; ++ni) { b1[ni][0] = rdB(buf, 1, ni, 0); b1[ni][1] = rdB(buf, 1, ni, 1); }
    if (U + 2 < NT) stageB(buf, U + 2, 0);
    __builtin_amdgcn_s_setprio(1);
    #pragma unroll
    for (int mi = 0; mi < 4; ++mi)
      #pragma unroll
      for (int ni = 0; ni < 2; ++ni) {
        acc[4 + mi][2 + ni] = __builtin_amdgcn_mfma_f32_16x16x32_bf16(a1[mi][0], b1[ni][0], acc[4 + mi][2 + ni], 0, 0, 0);
        acc[4 + mi][2 + ni] = __builtin_amdgcn_mfma_f32_16x16x32_bf16(a1[mi][1], b1[ni][1], acc[4 + mi][2 + ni], 0, 0, 0);
      }
    __builtin_amdgcn_s_setprio(0);
    __builtin_amdgcn_s_barrier();
    // ---- q3: (mh0, nh1) [no ds_reads]; stage A-mh1 of U+2 (last read at q1)
    if (U + 2 < NT) stageA(buf, U + 2, 1);
    __builtin_amdgcn_s_setprio(1);
    #pragma unroll
    for (int mi = 0; mi < 4; ++mi)
      #pragma unroll
      for (int ni = 0; ni < 2; ++ni) {
        acc[mi][2 + ni] = __builtin_amdgcn_mfma_f32_16x16x32_bf16(a0[mi][0], b1[ni][0], acc[mi][2 + ni], 0, 0, 0);
        acc[mi][2 + ni] = __builtin_amdgcn_mfma_f32_16x16x32_bf16(a0[mi][1], b1[ni][1], acc[mi][2 + ni], 0, 0, 0);
      }
    __builtin_amdgcn_s_setprio(0);
    // boundary: ensure tile U+1 resident; 4 loads (q2+q3 stages) may remain in flight
    if (U + 2 < NT) {
      asm volatile("s_waitcnt vmcnt(4)" ::: "memory");
    } else if (U + 1 < NT) {
      asm volatile("s_waitcnt vmcnt(0)" ::: "memory");
    }
    __builtin_amdgcn_sched_barrier(0);
    __builtin_amdgcn_s_barrier();
  }

  // ---------------- epilogue ----------------
  if (MODE == 0) {
    unsigned short* hs = (unsigned short*)Cout;
    unsigned short* base = hs + (size_t)ez * ((size_t)ncRows * Hd);
    #pragma unroll
    for (int M = 0; M < 8; ++M) {
      const int mh = M >> 2, mi = M & 3;
      const int row = bx * 256 + wm * 128 + mh * 64 + mi * 16 + (lane >> 4) * 4;
      float rw[4];
      #pragma unroll
      for (int j = 0; j < 4; ++j) rw[j] = route[(size_t)(n0 + row + j) * Ed + ez];
      #pragma unroll
      for (int N = 0; N < 4; ++N) {
        const int nh = N >> 1, ni = N & 1;
        const int col = by * 256 + wn * 64 + nh * 32 + ni * 16 + (lane & 15);
        const float bv = bias[ez * Hd + col];
        #pragma unroll
        for (int j = 0; j < 4; ++j) {
          float v = acc[M][N][j] + bv;
          v = fmaxf(v, 0.f);
          v = v * v * rw[j];
          base[(size_t)(row + j) * Hd + col] = f2bf(v);
        }
      }
    }
  } else {
    float* out = (float*)Cout;
    #pragma unroll
    for (int M = 0; M < 8; ++M) {
      const int mh = M >> 2, mi = M & 3;
      const int row = n0 + bx * 256 + wm * 128 + mh * 64 + mi * 16 + (lane >> 4) * 4;
      #pragma unroll
      for (int N = 0; N < 4; ++N) {
        const int nh = N >> 1, ni = N & 1;
        const int col = by * 256 + wn * 64 + nh * 32 + ni * 16 + (lane & 15);
        #pragma unroll
        for (int j = 0; j < 4; ++j)
          atomicAdd(out + (size_t)(row + j) * Od + col, acc[M][N][j]);
      }
    }
  }
}

extern "C" void kernel_launch(void* const* d_in, const int* in_sizes, int n_in,
                              void* d_out, int out_size, void* d_ws, size_t ws_size,
                              hipStream_t stream) {
  const float* x  = (const float*)d_in[0];
  const float* Wr = (const float*)d_in[1];
  const float* br = (const float*)d_in[2];
  const float* W1 = (const float*)d_in[3];
  const float* b1 = (const float*)d_in[4];
  const float* W2 = (const float*)d_in[5];
  const float* b2 = (const float*)d_in[6];
  float* out = (float*)d_out;

  char* ws = (char*)d_ws;
  size_t off = 0;
  float* route = (float*)(ws + off);                 off += (size_t)Nd * Ed * 4;
  unsigned short* xb  = (unsigned short*)(ws + off); off += (size_t)Nd * Dd * 2;
  unsigned short* w1b = (unsigned short*)(ws + off); off += (size_t)Ed * Hd * Dd * 2;
  unsigned short* w2b = (unsigned short*)(ws + off); off += (size_t)Ed * Od * Hd * 2;
  unsigned short* hs  = (unsigned short*)(ws + off);

  size_t remain = (ws_size > off) ? (ws_size - off) : 0;
  const size_t perRow = (size_t)Ed * Hd * 2;  // bytes of hs per token row
  long long ncMax = (long long)(remain / perRow);
  int NC = (int)(ncMax & ~255LL);
  if (NC > Nd) NC = Nd;
  if (NC < 256) NC = 256;

  hipFuncSetAttribute(reinterpret_cast<const void*>(&gemm8p<0>),
                      hipFuncAttributeMaxDynamicSharedMemorySize, 131072);
  hipFuncSetAttribute(reinterpret_cast<const void*>(&gemm8p<1>),
                      hipFuncAttributeMaxDynamicSharedMemorySize, 131072);

  cvt_kernel<<<2048, 256, 0, stream>>>(W1, w1b, Ed * Hd * Dd / 8);
  cvt_kernel<<<2048, 256, 0, stream>>>(W2, w2b, Ed * Od * Hd / 8);
  router_kernel<<<Nd, 256, 0, stream>>>(x, Wr, br, route, xb);
  init_out_kernel<<<Nd * Od / 256, 256, 0, stream>>>(route, b2, out);

  for (int n0 = 0; n0 < Nd; n0 += NC) {
    int nc = (NC < (Nd - n0)) ? NC : (Nd - n0);
    int ngx = nc / 256;
    gemm8p<0><<<ngx * 8 * Ed, 512, 131072, stream>>>(xb, w1b, b1, route, hs, n0, nc, ngx);
    gemm8p<1><<<ngx * 4 * 4, 512, 131072, stream>>>(hs, w2b, nullptr, nullptr, out, n0, nc, ngx);
  }
}